// Round 3
// baseline (4406.829 us; speedup 1.0000x reference)
//
#include <hip/hip_runtime.h>

namespace {

constexpr int T_STEPS = 32;
constexpr int BATCH   = 8192;
constexpr int H1      = 480;   // first dense layer
constexpr int HID     = 200;   // GRU hidden
constexpr int G3      = 600;   // 3*HID
constexpr int H2      = 320;   // second dense layer
constexpr int BR      = 8;     // batch rows per block
constexpr int NTHR    = 256;   // threads per block
constexpr int NWG     = H1 * G3;          // 288000
constexpr int NUG     = HID * G3;         // 120000
constexpr int NW2     = HID * H2;         // 64000
constexpr int NCVT    = NWG + NUG + NW2;  // 472000

__device__ __forceinline__ float sigmoid_(float x) {
    return 1.f / (1.f + __expf(-x));
}

__device__ __forceinline__ float tanh_(float x) {
    x = fminf(fmaxf(x, -15.f), 15.f);
    const float e = __expf(-2.f * x);
    return (1.f - e) / (1.f + e);
}

__device__ __forceinline__ float w2f(float w) { return w; }
__device__ __forceinline__ float w2f(unsigned short w) {
    return __uint_as_float(((unsigned int)w) << 16);
}

// read 8 contiguous floats from LDS via 2x ds_read_b128 (same addr across
// lanes -> broadcast, no bank conflicts)
__device__ __forceinline__ void load8(const float* __restrict__ p, float* a) {
    const float4* v = reinterpret_cast<const float4*>(p);
    const float4 t0 = v[0];
    const float4 t1 = v[1];
    a[0] = t0.x; a[1] = t0.y; a[2] = t0.z; a[3] = t0.w;
    a[4] = t1.x; a[5] = t1.y; a[6] = t1.z; a[7] = t1.w;
}

// fp32 -> bf16 (RNE) conversion of the three big weight matrices into d_ws
__global__ void cvt_kernel(const float* __restrict__ Wg,
                           const float* __restrict__ Ug,
                           const float* __restrict__ W2,
                           unsigned short* __restrict__ o) {
    const int i = blockIdx.x * 256 + threadIdx.x;
    if (i >= NCVT) return;
    float v;
    if (i < NWG)            v = Wg[i];
    else if (i < NWG + NUG) v = Ug[i - NWG];
    else                    v = W2[i - NWG - NUG];
    unsigned int u = __float_as_uint(v);
    u = (u + 0x7fffu + ((u >> 16) & 1u)) >> 16;
    o[i] = (unsigned short)u;
}

template <typename WT>
__global__ __launch_bounds__(NTHR, 4) void knet_kernel(
    const float* __restrict__ y,    // [T,B,2]
    const float* __restrict__ Fm,   // [4,4]
    const float* __restrict__ Hm,   // [2,4]
    const float* __restrict__ W1,   // [8,480]
    const float* __restrict__ b1,   // [480]
    const WT*    __restrict__ Wg,   // [480,600]
    const WT*    __restrict__ Ug,   // [200,600]
    const float* __restrict__ bg,   // [2,600]
    const WT*    __restrict__ W2,   // [200,320]
    const float* __restrict__ b2,   // [320]
    const float* __restrict__ W3,   // [320,8]
    const float* __restrict__ b3,   // [8]
    const float* __restrict__ hn0,  // [B,200]
    float* __restrict__ out)        // [T,B,4]
{
    // [feature][row] layout; rows of 8 floats = 32 B (16B-aligned for float4)
    __shared__ float s_hnt[HID][BR];          // 6.4 KB, single-buffered
    __shared__ float s_act[H1][BR];           // 15.4 KB, union: a1 (480) / a2 (320)
    __shared__ float s_y[T_STEPS][BR][2];     // 2 KB, y preloaded once
    __shared__ float s_in8[BR][9];            // +1 pad breaks stride-8 banks
    __shared__ float s_dm1y[BR][2];
    __shared__ float s_prior[BR][4];
    __shared__ float s_post[BR][4];
    __shared__ float s_kg[BR][8];

    const int tid  = threadIdx.x;
    const int row0 = blockIdx.x * BR;

    // ---- init: hn0 -> s_hnt (transpose), preload y slice, zero state ----
    for (int idx = tid; idx < BR * HID; idx += NTHR) {
        const int r = idx / HID;
        const int k = idx - r * HID;  // coalesced global read per row
        s_hnt[k][r] = hn0[(size_t)(row0 + r) * HID + k];
    }
    for (int idx = tid; idx < T_STEPS * BR * 2; idx += NTHR) {
        const int t   = idx / (BR * 2);
        const int rem = idx - t * (BR * 2);
        s_y[t][rem >> 1][rem & 1] = y[((size_t)t * BATCH + row0) * 2 + rem];
    }
    if (tid < BR * 4) {
        s_prior[tid >> 2][tid & 3] = 0.f;
        s_post[tid >> 2][tid & 3]  = 0.f;
    }
    __syncthreads();

    for (int t = 0; t < T_STEPS; ++t) {
        // ---- Phase A: per-row prior/innovation/features (BR threads) ----
        if (tid < BR) {
            const int r = tid;
            float post[4], prevpri[4], pri[4];
#pragma unroll
            for (int m = 0; m < 4; ++m) {
                post[m]    = s_post[r][m];
                prevpri[m] = s_prior[r][m];
            }
#pragma unroll
            for (int m = 0; m < 4; ++m) {
                float s = 0.f;
#pragma unroll
                for (int j = 0; j < 4; ++j) s += Fm[m * 4 + j] * post[j];
                pri[m] = s;
            }
            float dy[2];
#pragma unroll
            for (int n = 0; n < 2; ++n) {
                float s = 0.f;
#pragma unroll
                for (int m = 0; m < 4; ++m) s += Hm[n * 4 + m] * pri[m];
                dy[n] = s_y[t][r][n] - s;
            }
            float dx[4], ssx = 0.f;
#pragma unroll
            for (int m = 0; m < 4; ++m) {
                dx[m] = post[m] - prevpri[m];
                ssx += dx[m] * dx[m];
            }
            const float idx_ = rsqrtf(fmaxf(ssx, 1e-12f));
            const float ssy  = dy[0] * dy[0] + dy[1] * dy[1];
            const float idy_ = rsqrtf(fmaxf(ssy, 1e-12f));
            s_in8[r][0] = dy[0] * idy_;
            s_in8[r][1] = dy[1] * idy_;
            s_in8[r][2] = dy[0] * idy_;
            s_in8[r][3] = dy[1] * idy_;
#pragma unroll
            for (int m = 0; m < 4; ++m) s_in8[r][4 + m] = dx[m] * idx_;
            s_dm1y[r][0] = dy[0];
            s_dm1y[r][1] = dy[1];
#pragma unroll
            for (int m = 0; m < 4; ++m) s_prior[r][m] = pri[m];
        }
        __syncthreads();

        // ---- Phase B: a1[j][r] = relu(b1[j] + in8[r] . W1[:,j]) ----
        {
            const int r  = tid & (BR - 1);
            const int j0 = tid >> 3;  // 32 column slots
            float v[8];
#pragma unroll
            for (int k = 0; k < 8; ++k) v[k] = s_in8[r][k];
            for (int j = j0; j < H1; j += 32) {
                float s = b1[j];
#pragma unroll
                for (int k = 0; k < 8; ++k) s = fmaf(v[k], W1[k * H1 + j], s);
                s_act[j][r] = fmaxf(s, 0.f);
            }
        }
        __syncthreads();

        // ---- Phase C: fused GRU. thread j owns gate-column j, 8 rows ----
        float hnew[BR];
        if (tid < HID) {
            const int j = tid;
            float az[BR], ar_[BR], ahx[BR], ahh[BR];
#pragma unroll
            for (int r = 0; r < BR; ++r) { az[r] = 0.f; ar_[r] = 0.f; ahx[r] = 0.f; ahh[r] = 0.f; }

            const WT* wg = Wg + j;
            for (int k = 0; k < H1; ++k) {
                const float wz = w2f(wg[k * G3]);
                const float wr = w2f(wg[k * G3 + HID]);
                const float wh = w2f(wg[k * G3 + 2 * HID]);
                float a[BR];
                load8(&s_act[k][0], a);
#pragma unroll
                for (int r = 0; r < BR; ++r) {
                    az[r]  = fmaf(a[r], wz, az[r]);
                    ar_[r] = fmaf(a[r], wr, ar_[r]);
                    ahx[r] = fmaf(a[r], wh, ahx[r]);
                }
            }
            const WT* ug = Ug + j;
            for (int k = 0; k < HID; ++k) {
                const float uz = w2f(ug[k * G3]);
                const float ur = w2f(ug[k * G3 + HID]);
                const float uh = w2f(ug[k * G3 + 2 * HID]);
                float h[BR];
                load8(&s_hnt[k][0], h);
#pragma unroll
                for (int r = 0; r < BR; ++r) {
                    az[r]  = fmaf(h[r], uz, az[r]);
                    ar_[r] = fmaf(h[r], ur, ar_[r]);
                    ahh[r] = fmaf(h[r], uh, ahh[r]);
                }
            }
            const float bz  = bg[j] + bg[G3 + j];
            const float brr = bg[HID + j] + bg[G3 + HID + j];
            const float bhx = bg[2 * HID + j];
            const float bhh = bg[G3 + 2 * HID + j];
            float ho[BR];
            load8(&s_hnt[j][0], ho);
#pragma unroll
            for (int r = 0; r < BR; ++r) {
                const float z  = sigmoid_(az[r] + bz);
                const float rr = sigmoid_(ar_[r] + brr);
                const float hc = tanh_((ahx[r] + bhx) + rr * (ahh[r] + bhh));
                hnew[r] = z * ho[r] + (1.f - z) * hc;
            }
        }
        __syncthreads();  // all reads of old h / a1 complete
        if (tid < HID) {  // vectorized write: b128 stores hit the 8/bank floor
            float4* dst = reinterpret_cast<float4*>(&s_hnt[tid][0]);
            const float4* src = reinterpret_cast<const float4*>(hnew);
            dst[0] = src[0];
            dst[1] = src[1];
        }
        __syncthreads();

        // ---- Phase D: a2[j][r] = relu(b2[j] + hnew . W2[:,j]) ----
        for (int j = tid; j < H2; j += NTHR) {
            float acc[BR];
#pragma unroll
            for (int r = 0; r < BR; ++r) acc[r] = 0.f;
            for (int k = 0; k < HID; ++k) {
                const float w = w2f(W2[k * H2 + j]);
                float h[BR];
                load8(&s_hnt[k][0], h);
#pragma unroll
                for (int r = 0; r < BR; ++r) acc[r] = fmaf(h[r], w, acc[r]);
            }
            const float bb = b2[j];
            float o8[BR];
#pragma unroll
            for (int r = 0; r < BR; ++r) o8[r] = fmaxf(acc[r] + bb, 0.f);
            float4* dst = reinterpret_cast<float4*>(&s_act[j][0]);
            const float4* src = reinterpret_cast<const float4*>(o8);
            dst[0] = src[0];
            dst[1] = src[1];
        }
        __syncthreads();

        // ---- Phase E: KG[r][c] = b3[c] + a2 . W3[:,c]  (64 items) ----
        if (tid < BR * 8) {
            const int r = tid >> 3;
            const int c = tid & 7;
            float acc = b3[c];
            for (int k = 0; k < H2; ++k) acc = fmaf(s_act[k][r], W3[k * 8 + c], acc);
            s_kg[r][c] = acc;
        }
        __syncthreads();

        // ---- Phase F: posterior update + output write ----
        if (tid < BR) {
            const int r    = tid;
            const float d0 = s_dm1y[r][0];
            const float d1 = s_dm1y[r][1];
            float p[4];
#pragma unroll
            for (int m = 0; m < 4; ++m) {
                const float inov = s_kg[r][2 * m] * d0 + s_kg[r][2 * m + 1] * d1;
                p[m] = s_prior[r][m] + inov;
                s_post[r][m] = p[m];
            }
            *reinterpret_cast<float4*>(&out[((size_t)t * BATCH + row0 + r) * 4]) =
                *reinterpret_cast<const float4*>(p);
        }
        __syncthreads();
    }
}

}  // namespace

extern "C" void kernel_launch(void* const* d_in, const int* in_sizes, int n_in,
                              void* d_out, int out_size, void* d_ws, size_t ws_size,
                              hipStream_t stream) {
    const float* y   = (const float*)d_in[0];
    const float* Fm  = (const float*)d_in[1];
    const float* Hm  = (const float*)d_in[2];
    const float* W1  = (const float*)d_in[3];
    const float* b1  = (const float*)d_in[4];
    const float* Wg  = (const float*)d_in[5];
    const float* Ug  = (const float*)d_in[6];
    const float* bg  = (const float*)d_in[7];
    const float* W2  = (const float*)d_in[8];
    const float* b2  = (const float*)d_in[9];
    const float* W3  = (const float*)d_in[10];
    const float* b3  = (const float*)d_in[11];
    const float* hn0 = (const float*)d_in[12];
    float* out = (float*)d_out;

    dim3 grid(BATCH / BR);  // 1024 blocks, 4 per CU
    dim3 block(NTHR);

    if (ws_size >= (size_t)NCVT * sizeof(unsigned short)) {
        unsigned short* wbf = (unsigned short*)d_ws;
        cvt_kernel<<<(NCVT + 255) / 256, 256, 0, stream>>>(Wg, Ug, W2, wbf);
        knet_kernel<unsigned short><<<grid, block, 0, stream>>>(
            y, Fm, Hm, W1, b1, wbf, wbf + NWG, bg, wbf + NWG + NUG, b2,
            W3, b3, hn0, out);
    } else {
        knet_kernel<float><<<grid, block, 0, stream>>>(
            y, Fm, Hm, W1, b1, Wg, Ug, bg, W2, b2, W3, b3, hn0, out);
    }
}